// Round 1
// baseline (361.448 us; speedup 1.0000x reference)
//
#include <hip/hip_runtime.h>

// ---------------------------------------------------------------------------
// STCAOutputLayer: h = x@w (bf16 MFMA GEMM); E==0 identically (spk never set),
// out[b,t,d] = (M_t - S_t)*inv_norm[d] - bias[d],
// M_t = dm*(M_{t-1}+h_t), S_t = ds*(S_{t-1}+h_t); loss = 0.5*mean(out^2).
// Shapes: B=32 T=500 IN=2048 OUT=1024; M=B*T=16000, N=1024, K=2048.
//
// R2: 128x256 2-barrier GEMM (m97 structure) -> LDS/drain bound, ~40% MfmaUtil.
// R3: GEMM rebuilt as counted-vmcnt pipeline (T3+T4+T5 stack):
//     BM=BN=256, BK=32, 8 waves, per-wave 128x64 (8x4 frags of 16x16x32).
//     4 LDS buffers x 32KB, prefetch depth 3, boundary s_waitcnt vmcnt(12)
//     (never 0 mid-loop), raw s_barrier (no implicit vmcnt drain),
//     s_setprio(1) around each 16-MFMA cluster. seg^((row>>1)&3) swizzle on
//     64B rows keeps ds_read_b128 at 2-way (free). Grid 63x4=252 blocks,
//     1 block/CU, bijective XCD swizzle (252%8=4 -> m204 formula).
// ---------------------------------------------------------------------------

typedef __bf16 bf16x8 __attribute__((ext_vector_type(8)));
typedef __bf16 bf16x4 __attribute__((ext_vector_type(4)));
typedef float  f32x4  __attribute__((ext_vector_type(4)));

#define BDIM 32
#define TDIM 500
#define INDIM 2048
#define OUTDIM 1024
#define MROWS 16000            // B*T
#define NCHUNK 25              // scan chunks
#define CHLEN 20               // 25*20 = 500
#define OUT_ELEMS 16384000     // B*T*OUT

// ---- global -> LDS async copy, 16B per lane, LDS dest = base + lane*16 ----
__device__ __forceinline__ void gld_lds16(const void* g, void* l) {
    __builtin_amdgcn_global_load_lds(
        (const __attribute__((address_space(1))) unsigned int*)g,
        (__attribute__((address_space(3))) unsigned int*)l, 16, 0, 0);
}

// ---------------------------------------------------------------------------
// fp32 -> bf16 convert of x (pure elementwise). 8 elems / thread.
__global__ void convert_x(const float* __restrict__ x, __bf16* __restrict__ xb) {
    size_t i = ((size_t)blockIdx.x * 256 + threadIdx.x) * 8;
    float4 a = *(const float4*)(x + i);
    float4 b = *(const float4*)(x + i + 4);
    bf16x8 o;
    o[0] = (__bf16)a.x; o[1] = (__bf16)a.y; o[2] = (__bf16)a.z; o[3] = (__bf16)a.w;
    o[4] = (__bf16)b.x; o[5] = (__bf16)b.y; o[6] = (__bf16)b.z; o[7] = (__bf16)b.w;
    *(bf16x8*)(xb + i) = o;
}

// ---------------------------------------------------------------------------
// w [K=2048][N=1024] fp32 -> wbt [N][K] bf16, with fused norm[d]=sum_c w^2
__global__ void transpose_w(const float* __restrict__ w, __bf16* __restrict__ wbt,
                            float* __restrict__ normAcc) {
    __shared__ float tile[32][33];
    __shared__ float red[8][33];
    const int tx = threadIdx.x;        // 0..31
    const int ty = threadIdx.y;        // 0..7
    const int d0 = blockIdx.x * 32;    // N tile
    const int c0 = blockIdx.y * 32;    // K tile
    float s = 0.f;
#pragma unroll
    for (int i = 0; i < 4; ++i) {
        int c = c0 + ty + i * 8;
        float v = w[(size_t)c * OUTDIM + d0 + tx];
        tile[ty + i * 8][tx] = v;
        s += v * v;
    }
    red[ty][tx] = s;
    __syncthreads();
#pragma unroll
    for (int i = 0; i < 4; ++i) {
        int d = d0 + ty + i * 8;
        wbt[(size_t)d * INDIM + c0 + tx] = (__bf16)tile[tx][ty + i * 8];
    }
    if (ty == 0) {
        float t = red[0][tx] + red[1][tx] + red[2][tx] + red[3][tx]
                + red[4][tx] + red[5][tx] + red[6][tx] + red[7][tx];
        atomicAdd(&normAcc[d0 + tx], t);
    }
}

// ---------------------------------------------------------------------------
// GEMM: H[m][n] = sum_k A[m][k]*Bt[n][k], bf16 in/out (fp32 acc).
// Counted-vmcnt 4-deep pipeline; see header comment. Per K-tile (BK=32):
//   phase0: ds_read A(i=0..3)+B(j=0..3) -> barrier -> 16 MFMA -> barrier
//   phase1: ds_read A(i=4..7)           -> barrier -> 16 MFMA -> barrier
//   boundary: issue stage(t+4) into just-freed buf; vmcnt(12); barrier
__global__ __launch_bounds__(512, 2) void gemm_bf16(
    const __bf16* __restrict__ A,   // [16000][2048]  (xb, lives in d_out)
    const __bf16* __restrict__ Bt,  // [1024][2048]
    __bf16* __restrict__ H)         // [16000][1024]
{
    constexpr int K  = INDIM;
    constexpr int NT = K / 32;                       // 64 K-tiles
    __shared__ __align__(16) __bf16 As[4][256 * 32]; // 4 x 16KB
    __shared__ __align__(16) __bf16 Bs[4][256 * 32]; // 4 x 16KB

    const int tid  = threadIdx.x;
    const int wave = tid >> 6;          // 0..7
    const int lane = tid & 63;
    const int wm   = wave >> 2;         // 0..1 : 128-row output band
    const int wn   = wave & 3;          // 0..3 : 64-col output band

    // bijective XCD swizzle over 252 blocks (252 = 8*31 + 4)
    const int orig = blockIdx.x;
    const int xcd = orig & 7, within = orig >> 3;
    const int wgid = (xcd < 4) ? (xcd * 32 + within)
                               : (128 + (xcd - 4) * 31 + within);
    const int bm = (wgid >> 2) * 256;   // 0..15872 (last block: 128 valid rows)
    const int bn = (wgid & 3) * 256;

    // staging: one gld_lds = 1KB = 16 rows x 64B. lane -> (row=lane>>2, seg=lane&3).
    // LDS kept linear; swizzle realized by pre-swizzling the GLOBAL column.
    const int srow = lane >> 2;
    const int sseg = lane & 3;
    const int scol = (sseg ^ ((srow >> 1) & 3)) * 8;     // elems
    const int lds0 = (wave * 16) * 32;                   // stmt g=0 rows
    const int lds1 = (128 + wave * 16) * 32;             // stmt g=1 rows
    int rA0 = bm +       wave * 16 + srow; if (rA0 > MROWS - 1) rA0 = MROWS - 1;
    int rA1 = bm + 128 + wave * 16 + srow; if (rA1 > MROWS - 1) rA1 = MROWS - 1;
    const __bf16* gA0 = A  + (size_t)rA0 * K + scol;
    const __bf16* gA1 = A  + (size_t)rA1 * K + scol;
    const __bf16* gB0 = Bt + (size_t)(bn +       wave * 16 + srow) * K + scol;
    const __bf16* gB1 = Bt + (size_t)(bn + 128 + wave * 16 + srow) * K + scol;

    // fragment reads: row = band + i*16 + mrow, seg = quad ^ ((mrow>>1)&3)
    const int mrow = lane & 15, quad = lane >> 4;
    const int swzq = quad ^ ((mrow >> 1) & 3);
    const int rdA = (wm * 128 + mrow) * 32 + swzq * 8;
    const int rdB = (wn * 64  + mrow) * 32 + swzq * 8;

    f32x4 acc[8][4] = {};

#define STAGE(tt) do { const int _b = (tt) & 3; const size_t _k = (size_t)(tt) * 32; \
        gld_lds16(gA0 + _k, &As[_b][lds0]);                                          \
        gld_lds16(gA1 + _k, &As[_b][lds1]);                                          \
        gld_lds16(gB0 + _k, &Bs[_b][lds0]);                                          \
        gld_lds16(gB1 + _k, &Bs[_b][lds1]); } while (0)

    // prologue: tiles 0..3 in flight; wait tile0 (12 = 3 tiles x 4 loads left)
    STAGE(0); STAGE(1); STAGE(2); STAGE(3);
    asm volatile("s_waitcnt vmcnt(12)" ::: "memory");
    asm volatile("s_barrier" ::: "memory");

#pragma unroll 1
    for (int t = 0; t < NT; ++t) {
        const __bf16* as = As[t & 3];
        const __bf16* bs = Bs[t & 3];
        bf16x8 af[4], bfr[4];
        // ---- phase 0: A frags 0..3 + all B frags ----
#pragma unroll
        for (int i = 0; i < 4; ++i) af[i]  = *(const bf16x8*)&as[rdA + i * 512];
#pragma unroll
        for (int j = 0; j < 4; ++j) bfr[j] = *(const bf16x8*)&bs[rdB + j * 512];
        asm volatile("s_barrier" ::: "memory");
        __builtin_amdgcn_s_setprio(1);
#pragma unroll
        for (int i = 0; i < 4; ++i)
#pragma unroll
            for (int j = 0; j < 4; ++j)
                acc[i][j] = __builtin_amdgcn_mfma_f32_16x16x32_bf16(
                    af[i], bfr[j], acc[i][j], 0, 0, 0);
        __builtin_amdgcn_s_setprio(0);
        asm volatile("s_barrier" ::: "memory");
        // ---- phase 1: A frags 4..7, B held in regs ----
#pragma unroll
        for (int i = 0; i < 4; ++i) af[i] = *(const bf16x8*)&as[rdA + 2048 + i * 512];
        asm volatile("s_barrier" ::: "memory");
        __builtin_amdgcn_s_setprio(1);
#pragma unroll
        for (int i = 0; i < 4; ++i)
#pragma unroll
            for (int j = 0; j < 4; ++j)
                acc[4 + i][j] = __builtin_amdgcn_mfma_f32_16x16x32_bf16(
                    af[i], bfr[j], acc[4 + i][j], 0, 0, 0);
        __builtin_amdgcn_s_setprio(0);
        asm volatile("s_barrier" ::: "memory");   // all reads of buf[t&3] done
        // ---- boundary: refill freed buffer, ensure tile t+1 resident ----
        if (t + 4 < NT) STAGE(t + 4);
        if (t < NT - 4)       asm volatile("s_waitcnt vmcnt(12)" ::: "memory");
        else if (t == NT - 4) asm volatile("s_waitcnt vmcnt(8)"  ::: "memory");
        else if (t == NT - 3) asm volatile("s_waitcnt vmcnt(4)"  ::: "memory");
        else if (t == NT - 2) asm volatile("s_waitcnt vmcnt(0)"  ::: "memory");
        if (t < NT - 1) asm volatile("s_barrier" ::: "memory");
    }
#undef STAGE

    // epilogue: D[row=quad*4+reg][col=mrow] (m89-verified layout)
    const int Rb = bm + wm * 128 + quad * 4;
    const int Cb = bn + wn * 64 + mrow;
#pragma unroll
    for (int i = 0; i < 8; ++i)
#pragma unroll
        for (int j = 0; j < 4; ++j)
#pragma unroll
            for (int r = 0; r < 4; ++r) {
                const int R = Rb + i * 16 + r;
                if (R < MROWS)
                    H[(size_t)R * OUTDIM + Cb + j * 16] = (__bf16)acc[i][j][r];
            }
}

// ---------------------------------------------------------------------------
// scan pass 1: per (chunk c, batch b): local M/S with zero carry-in; store
// chunk-end values.  256 threads cover all 1024 d (float4 each).
__global__ void scan1(const __bf16* __restrict__ H,
                      f32x4* __restrict__ cM, f32x4* __restrict__ cS,
                      const float* __restrict__ dmp, const float* __restrict__ dsp) {
    const float dm = *dmp, ds = *dsp;
    const int c = blockIdx.x, b = blockIdx.y, tid = threadIdx.x;
    f32x4 M = {}, S = {};
    const __bf16* p = H + ((size_t)b * TDIM + c * CHLEN) * OUTDIM + tid * 4;
#pragma unroll 4
    for (int t = 0; t < CHLEN; ++t) {
        bf16x4 hv = *(const bf16x4*)(p + (size_t)t * OUTDIM);
        f32x4 h; h[0] = hv[0]; h[1] = hv[1]; h[2] = hv[2]; h[3] = hv[3];
        M = dm * (M + h);
        S = ds * (S + h);
    }
    const size_t idx = ((size_t)c * BDIM + b) * 256 + tid;
    cM[idx] = M;
    cS[idx] = S;
}

// ---------------------------------------------------------------------------
// scan pass 2: chunk-end values -> per-chunk carry-INs (in place).
__global__ void scan2(float* __restrict__ cM, float* __restrict__ cS,
                      const float* __restrict__ dmp, const float* __restrict__ dsp) {
    const float dm = *dmp, ds = *dsp;
    float km = 1.f, ks = 1.f;
#pragma unroll
    for (int i = 0; i < CHLEN; ++i) { km *= dm; ks *= ds; }
    const int gid = blockIdx.x * 256 + threadIdx.x;   // 0..32767
    const int b = gid >> 10, d = gid & 1023;
    float tM = 0.f, tS = 0.f;
    for (int c = 0; c < NCHUNK; ++c) {
        const size_t idx = (((size_t)c * BDIM + b) << 10) + d;
        float oM = cM[idx], oS = cS[idx];
        cM[idx] = tM; cS[idx] = tS;
        tM = km * tM + oM;
        tS = ks * tS + oS;
    }
}

// ---------------------------------------------------------------------------
// scan pass 3: recompute with carry-in, write out, accumulate loss; last
// block (device-scope ticket) writes the final loss scalar.
__global__ void scan3(const __bf16* __restrict__ H,
                      const f32x4* __restrict__ cM, const f32x4* __restrict__ cS,
                      const float* __restrict__ normAcc, const float* __restrict__ bias,
                      const float* __restrict__ dmp, const float* __restrict__ dsp,
                      float* __restrict__ out, float* __restrict__ lossAcc,
                      unsigned* __restrict__ ticket) {
    const float dm = *dmp, ds = *dsp;
    const int c = blockIdx.x, b = blockIdx.y, tid = threadIdx.x;
    const size_t cidx = ((size_t)c * BDIM + b) * 256 + tid;
    f32x4 M = cM[cidx];
    f32x4 S = cS[cidx];
    f32x4 nv = *(const f32x4*)(normAcc + tid * 4);
    f32x4 inv;
    inv[0] = 1.f / (nv[0] + 1e-8f); inv[1] = 1.f / (nv[1] + 1e-8f);
    inv[2] = 1.f / (nv[2] + 1e-8f); inv[3] = 1.f / (nv[3] + 1e-8f);
    f32x4 bv = *(const f32x4*)(bias + tid * 4);

    const size_t rowbase = ((size_t)b * TDIM + c * CHLEN) * OUTDIM + tid * 4;
    const __bf16* p = H + rowbase;
    float* o = out + rowbase;
    float loss = 0.f;
#pragma unroll 4
    for (int t = 0; t < CHLEN; ++t) {
        bf16x4 hv = *(const bf16x4*)(p + (size_t)t * OUTDIM);
        f32x4 h; h[0] = hv[0]; h[1] = hv[1]; h[2] = hv[2]; h[3] = hv[3];
        M = dm * (M + h);
        S = ds * (S + h);
        f32x4 r = (M - S) * inv - bv;
        *(f32x4*)(o + (size_t)t * OUTDIM) = r;
        loss += r[0] * r[0] + r[1] * r[1] + r[2] * r[2] + r[3] * r[3];
    }
    __shared__ float red[256];
    red[tid] = loss;
    __syncthreads();
    for (int s = 128; s > 0; s >>= 1) {
        if (tid < s) red[tid] += red[tid + s];
        __syncthreads();
    }
    if (tid == 0) {
        atomicAdd(lossAcc, red[0]);
        __threadfence();
        unsigned t = atomicAdd(ticket, 1u);
        if (t == NCHUNK * BDIM - 1) {
            float total = atomicAdd(lossAcc, 0.0f);   // coherent read
            out[OUT_ELEMS] = 0.5f * total / (float)OUT_ELEMS;
        }
    }
}

// ---------------------------------------------------------------------------
// Workspace layout (bytes):
//   H      (bf16 16000x1024) : 0          .. 32,768,000
//   WBT    (bf16 1024x2048)  : 32,768,000 .. 36,962,304
//   NORM   (f32 1024)        : 36,962,304 .. +4096
//   LOSS   (f32 1)           : 36,966,400
//   TICKET (u32 1)           : 36,966,404
//   CM     (f32 25*32*1024)  : 36,966,656 .. +3,276,800
//   CS                       : 40,243,456 .. +3,276,800   (end 43,520,256)
// xb (bf16 x) lives in d_out (exactly 65,536,000 B) until scan3 overwrites it.
#define OFF_H      ((size_t)0)
#define OFF_WBT    ((size_t)32768000)
#define OFF_NORM   ((size_t)36962304)
#define OFF_LOSS   ((size_t)36966400)
#define OFF_TICKET ((size_t)36966404)
#define OFF_CM     ((size_t)36966656)
#define OFF_CS     ((size_t)40243456)

extern "C" void kernel_launch(void* const* d_in, const int* in_sizes, int n_in,
                              void* d_out, int out_size, void* d_ws, size_t ws_size,
                              hipStream_t stream) {
    const float* x  = (const float*)d_in[0];
    const float* w  = (const float*)d_in[1];
    const float* bb = (const float*)d_in[2];
    const float* dm = (const float*)d_in[3];
    const float* ds = (const float*)d_in[4];

    char* ws = (char*)d_ws;
    __bf16*   H    = (__bf16*)(ws + OFF_H);
    __bf16*   WBT  = (__bf16*)(ws + OFF_WBT);
    float*    NORM = (float*)(ws + OFF_NORM);
    float*    LOSS = (float*)(ws + OFF_LOSS);
    unsigned* TICK = (unsigned*)(ws + OFF_TICKET);
    f32x4*    CM   = (f32x4*)(ws + OFF_CM);
    f32x4*    CS   = (f32x4*)(ws + OFF_CS);
    __bf16*   XB   = (__bf16*)d_out;          // scratch: bf16 x (exact fit)
    float*    out  = (float*)d_out;

    hipMemsetAsync(ws + OFF_NORM, 0, 4096 + 256, stream);   // NORM+LOSS+TICKET

    convert_x<<<16000, 256, 0, stream>>>(x, XB);
    transpose_w<<<dim3(32, 64), dim3(32, 8), 0, stream>>>(w, WBT, NORM);
    gemm_bf16<<<252, 512, 0, stream>>>(XB, WBT, H);
    scan1<<<dim3(NCHUNK, BDIM), 256, 0, stream>>>(H, CM, CS, dm, ds);
    scan2<<<128, 256, 0, stream>>>((float*)CM, (float*)CS, dm, ds);
    scan3<<<dim3(NCHUNK, BDIM), 256, 0, stream>>>(H, CM, CS, NORM, bb, dm, ds,
                                                  out, LOSS, TICK);
}

// Round 2
// 347.326 us; speedup vs baseline: 1.0407x; 1.0407x over previous
//
#include <hip/hip_runtime.h>

// ---------------------------------------------------------------------------
// STCAOutputLayer: h = x@w (bf16 MFMA GEMM); E==0 identically (spk never set),
// out[b,t,d] = (M_t - S_t)*inv_norm[d] - bias[d],
// M_t = dm*(M_{t-1}+h_t), S_t = ds*(S_{t-1}+h_t); loss = 0.5*mean(out^2).
// Shapes: B=32 T=500 IN=2048 OUT=1024; M=B*T=16000, N=1024, K=2048.
//
// R3: 256x256 counted-vmcnt pipeline, 5 barriers/tile -> 680 TF (27% MfmaUtil)
//     — intra-tile barriers serialized LDS-read vs MFMA phases (no cross-wave
//     hazard existed between them; pure loss).
// R4: same choreography, 2 barriers/tile: one fused region {12 ds_read_b128 +
//     32 MFMA} per tile (compiler interleaves via fine lgkmcnt), then
//     barrier -> STAGE(t+4) -> vmcnt(12) -> barrier. Never drains vmcnt
//     mid-loop. setprio dropped (null off 8-phase; perturbs sched regions).
// ---------------------------------------------------------------------------

typedef __bf16 bf16x8 __attribute__((ext_vector_type(8)));
typedef __bf16 bf16x4 __attribute__((ext_vector_type(4)));
typedef float  f32x4  __attribute__((ext_vector_type(4)));

#define BDIM 32
#define TDIM 500
#define INDIM 2048
#define OUTDIM 1024
#define MROWS 16000            // B*T
#define NCHUNK 25              // scan chunks
#define CHLEN 20               // 25*20 = 500
#define OUT_ELEMS 16384000     // B*T*OUT

// ---- global -> LDS async copy, 16B per lane, LDS dest = base + lane*16 ----
__device__ __forceinline__ void gld_lds16(const void* g, void* l) {
    __builtin_amdgcn_global_load_lds(
        (const __attribute__((address_space(1))) unsigned int*)g,
        (__attribute__((address_space(3))) unsigned int*)l, 16, 0, 0);
}

// ---------------------------------------------------------------------------
// fp32 -> bf16 convert of x (pure elementwise). 8 elems / thread.
__global__ void convert_x(const float* __restrict__ x, __bf16* __restrict__ xb) {
    size_t i = ((size_t)blockIdx.x * 256 + threadIdx.x) * 8;
    float4 a = *(const float4*)(x + i);
    float4 b = *(const float4*)(x + i + 4);
    bf16x8 o;
    o[0] = (__bf16)a.x; o[1] = (__bf16)a.y; o[2] = (__bf16)a.z; o[3] = (__bf16)a.w;
    o[4] = (__bf16)b.x; o[5] = (__bf16)b.y; o[6] = (__bf16)b.z; o[7] = (__bf16)b.w;
    *(bf16x8*)(xb + i) = o;
}

// ---------------------------------------------------------------------------
// w [K=2048][N=1024] fp32 -> wbt [N][K] bf16, with fused norm[d]=sum_c w^2
__global__ void transpose_w(const float* __restrict__ w, __bf16* __restrict__ wbt,
                            float* __restrict__ normAcc) {
    __shared__ float tile[32][33];
    __shared__ float red[8][33];
    const int tx = threadIdx.x;        // 0..31
    const int ty = threadIdx.y;        // 0..7
    const int d0 = blockIdx.x * 32;    // N tile
    const int c0 = blockIdx.y * 32;    // K tile
    float s = 0.f;
#pragma unroll
    for (int i = 0; i < 4; ++i) {
        int c = c0 + ty + i * 8;
        float v = w[(size_t)c * OUTDIM + d0 + tx];
        tile[ty + i * 8][tx] = v;
        s += v * v;
    }
    red[ty][tx] = s;
    __syncthreads();
#pragma unroll
    for (int i = 0; i < 4; ++i) {
        int d = d0 + ty + i * 8;
        wbt[(size_t)d * INDIM + c0 + tx] = (__bf16)tile[tx][ty + i * 8];
    }
    if (ty == 0) {
        float t = red[0][tx] + red[1][tx] + red[2][tx] + red[3][tx]
                + red[4][tx] + red[5][tx] + red[6][tx] + red[7][tx];
        atomicAdd(&normAcc[d0 + tx], t);
    }
}

// ---------------------------------------------------------------------------
// GEMM: H[m][n] = sum_k A[m][k]*Bt[n][k], bf16 in/out (fp32 acc).
// BM=BN=256, BK=32, 8 waves, per-wave 128x64 (8x4 frags of 16x16x32).
// 4 LDS buffers x 32KB, prefetch depth 3, boundary s_waitcnt vmcnt(12)
// (never 0 mid-loop), raw s_barrier (no implicit drain). 2 barriers/tile:
//   { 8 A-frag + 4 B-frag ds_read_b128, 32 MFMA }   <- one sched region
//   barrier; STAGE(t+4); vmcnt(12); barrier
// Hazard proof: tile-entry barrier follows the vmcnt that lands tile t;
// post-region barrier follows each wave's final MFMA, which the compiler
// guards with lgkmcnt on all 12 reads -> buf[t&3] fully read block-wide
// before STAGE(t+4) overwrites it.
__global__ __launch_bounds__(512, 2) void gemm_bf16(
    const __bf16* __restrict__ A,   // [16000][2048]  (xb, lives in d_out)
    const __bf16* __restrict__ Bt,  // [1024][2048]
    __bf16* __restrict__ H)         // [16000][1024]
{
    constexpr int K  = INDIM;
    constexpr int NT = K / 32;                       // 64 K-tiles
    __shared__ __align__(16) __bf16 As[4][256 * 32]; // 4 x 16KB
    __shared__ __align__(16) __bf16 Bs[4][256 * 32]; // 4 x 16KB

    const int tid  = threadIdx.x;
    const int wave = tid >> 6;          // 0..7
    const int lane = tid & 63;
    const int wm   = wave >> 2;         // 0..1 : 128-row output band
    const int wn   = wave & 3;          // 0..3 : 64-col output band

    // bijective XCD swizzle over 252 blocks (252 = 8*31 + 4); the 4 bn-blocks
    // of one A-panel stay consecutive -> same XCD chunk -> L2 panel reuse.
    const int orig = blockIdx.x;
    const int xcd = orig & 7, within = orig >> 3;
    const int wgid = (xcd < 4) ? (xcd * 32 + within)
                               : (128 + (xcd - 4) * 31 + within);
    const int bm = (wgid >> 2) * 256;   // 0..15872 (last block: 128 valid rows)
    const int bn = (wgid & 3) * 256;

    // staging: one gld_lds = 1KB = 16 rows x 64B. lane -> (row=lane>>2, seg=lane&3).
    // LDS kept linear; swizzle realized by pre-swizzling the GLOBAL column.
    const int srow = lane >> 2;
    const int sseg = lane & 3;
    const int scol = (sseg ^ ((srow >> 1) & 3)) * 8;     // elems
    const int lds0 = (wave * 16) * 32;                   // stmt g=0 rows
    const int lds1 = (128 + wave * 16) * 32;             // stmt g=1 rows
    int rA0 = bm +       wave * 16 + srow; if (rA0 > MROWS - 1) rA0 = MROWS - 1;
    int rA1 = bm + 128 + wave * 16 + srow; if (rA1 > MROWS - 1) rA1 = MROWS - 1;
    const __bf16* gA0 = A  + (size_t)rA0 * K + scol;
    const __bf16* gA1 = A  + (size_t)rA1 * K + scol;
    const __bf16* gB0 = Bt + (size_t)(bn +       wave * 16 + srow) * K + scol;
    const __bf16* gB1 = Bt + (size_t)(bn + 128 + wave * 16 + srow) * K + scol;

    // fragment reads: row = band + i*16 + mrow, seg = quad ^ ((mrow>>1)&3)
    const int mrow = lane & 15, quad = lane >> 4;
    const int swzq = quad ^ ((mrow >> 1) & 3);
    const int rdA = (wm * 128 + mrow) * 32 + swzq * 8;
    const int rdB = (wn * 64  + mrow) * 32 + swzq * 8;

    f32x4 acc[8][4] = {};

#define STAGE(tt) do { const int _b = (tt) & 3; const size_t _k = (size_t)(tt) * 32; \
        gld_lds16(gA0 + _k, &As[_b][lds0]);                                          \
        gld_lds16(gA1 + _k, &As[_b][lds1]);                                          \
        gld_lds16(gB0 + _k, &Bs[_b][lds0]);                                          \
        gld_lds16(gB1 + _k, &Bs[_b][lds1]); } while (0)

    // prologue: tiles 0..3 in flight; wait tile0 (12 = 3 tiles x 4 loads left)
    STAGE(0); STAGE(1); STAGE(2); STAGE(3);
    asm volatile("s_waitcnt vmcnt(12)" ::: "memory");
    asm volatile("s_barrier" ::: "memory");

#pragma unroll 1
    for (int t = 0; t < NT; ++t) {
        const __bf16* as = As[t & 3];
        const __bf16* bs = Bs[t & 3];
        bf16x8 af[8], bfr[4];
        // ---- one region: all frag reads + all MFMAs (compiler interleaves,
        //      waves skew freely -> LDS pipe and MFMA pipe overlap) ----
#pragma unroll
        for (int i = 0; i < 8; ++i) af[i]  = *(const bf16x8*)&as[rdA + i * 512];
#pragma unroll
        for (int j = 0; j < 4; ++j) bfr[j] = *(const bf16x8*)&bs[rdB + j * 512];
#pragma unroll
        for (int i = 0; i < 8; ++i)
#pragma unroll
            for (int j = 0; j < 4; ++j)
                acc[i][j] = __builtin_amdgcn_mfma_f32_16x16x32_bf16(
                    af[i], bfr[j], acc[i][j], 0, 0, 0);
        // all reads of buf[t&3] complete for this wave (lgkmcnt before MFMA);
        // barrier makes that block-wide before the refill.
        asm volatile("s_barrier" ::: "memory");
        // ---- boundary: refill freed buffer, ensure tile t+1 resident ----
        if (t + 4 < NT) STAGE(t + 4);
        if (t < NT - 4)       asm volatile("s_waitcnt vmcnt(12)" ::: "memory");
        else if (t == NT - 4) asm volatile("s_waitcnt vmcnt(8)"  ::: "memory");
        else if (t == NT - 3) asm volatile("s_waitcnt vmcnt(4)"  ::: "memory");
        else if (t == NT - 2) asm volatile("s_waitcnt vmcnt(0)"  ::: "memory");
        if (t < NT - 1) asm volatile("s_barrier" ::: "memory");
    }
#undef STAGE

    // epilogue: D[row=quad*4+reg][col=mrow] (m89-verified layout)
    const int Rb = bm + wm * 128 + quad * 4;
    const int Cb = bn + wn * 64 + mrow;
#pragma unroll
    for (int i = 0; i < 8; ++i)
#pragma unroll
        for (int j = 0; j < 4; ++j)
#pragma unroll
            for (int r = 0; r < 4; ++r) {
                const int R = Rb + i * 16 + r;
                if (R < MROWS)
                    H[(size_t)R * OUTDIM + Cb + j * 16] = (__bf16)acc[i][j][r];
            }
}

// ---------------------------------------------------------------------------
// scan pass 1: per (chunk c, batch b): local M/S with zero carry-in; store
// chunk-end values.  256 threads cover all 1024 d (float4 each).
__global__ void scan1(const __bf16* __restrict__ H,
                      f32x4* __restrict__ cM, f32x4* __restrict__ cS,
                      const float* __restrict__ dmp, const float* __restrict__ dsp) {
    const float dm = *dmp, ds = *dsp;
    const int c = blockIdx.x, b = blockIdx.y, tid = threadIdx.x;
    f32x4 M = {}, S = {};
    const __bf16* p = H + ((size_t)b * TDIM + c * CHLEN) * OUTDIM + tid * 4;
#pragma unroll 4
    for (int t = 0; t < CHLEN; ++t) {
        bf16x4 hv = *(const bf16x4*)(p + (size_t)t * OUTDIM);
        f32x4 h; h[0] = hv[0]; h[1] = hv[1]; h[2] = hv[2]; h[3] = hv[3];
        M = dm * (M + h);
        S = ds * (S + h);
    }
    const size_t idx = ((size_t)c * BDIM + b) * 256 + tid;
    cM[idx] = M;
    cS[idx] = S;
}

// ---------------------------------------------------------------------------
// scan pass 2: chunk-end values -> per-chunk carry-INs (in place).
__global__ void scan2(float* __restrict__ cM, float* __restrict__ cS,
                      const float* __restrict__ dmp, const float* __restrict__ dsp) {
    const float dm = *dmp, ds = *dsp;
    float km = 1.f, ks = 1.f;
#pragma unroll
    for (int i = 0; i < CHLEN; ++i) { km *= dm; ks *= ds; }
    const int gid = blockIdx.x * 256 + threadIdx.x;   // 0..32767
    const int b = gid >> 10, d = gid & 1023;
    float tM = 0.f, tS = 0.f;
    for (int c = 0; c < NCHUNK; ++c) {
        const size_t idx = (((size_t)c * BDIM + b) << 10) + d;
        float oM = cM[idx], oS = cS[idx];
        cM[idx] = tM; cS[idx] = tS;
        tM = km * tM + oM;
        tS = ks * tS + oS;
    }
}

// ---------------------------------------------------------------------------
// scan pass 3: recompute with carry-in, write out, accumulate loss; last
// block (device-scope ticket) writes the final loss scalar.
__global__ void scan3(const __bf16* __restrict__ H,
                      const f32x4* __restrict__ cM, const f32x4* __restrict__ cS,
                      const float* __restrict__ normAcc, const float* __restrict__ bias,
                      const float* __restrict__ dmp, const float* __restrict__ dsp,
                      float* __restrict__ out, float* __restrict__ lossAcc,
                      unsigned* __restrict__ ticket) {
    const float dm = *dmp, ds = *dsp;
    const int c = blockIdx.x, b = blockIdx.y, tid = threadIdx.x;
    const size_t cidx = ((size_t)c * BDIM + b) * 256 + tid;
    f32x4 M = cM[cidx];
    f32x4 S = cS[cidx];
    f32x4 nv = *(const f32x4*)(normAcc + tid * 4);
    f32x4 inv;
    inv[0] = 1.f / (nv[0] + 1e-8f); inv[1] = 1.f / (nv[1] + 1e-8f);
    inv[2] = 1.f / (nv[2] + 1e-8f); inv[3] = 1.f / (nv[3] + 1e-8f);
    f32x4 bv = *(const f32x4*)(bias + tid * 4);

    const size_t rowbase = ((size_t)b * TDIM + c * CHLEN) * OUTDIM + tid * 4;
    const __bf16* p = H + rowbase;
    float* o = out + rowbase;
    float loss = 0.f;
#pragma unroll 4
    for (int t = 0; t < CHLEN; ++t) {
        bf16x4 hv = *(const bf16x4*)(p + (size_t)t * OUTDIM);
        f32x4 h; h[0] = hv[0]; h[1] = hv[1]; h[2] = hv[2]; h[3] = hv[3];
        M = dm * (M + h);
        S = ds * (S + h);
        f32x4 r = (M - S) * inv - bv;
        *(f32x4*)(o + (size_t)t * OUTDIM) = r;
        loss += r[0] * r[0] + r[1] * r[1] + r[2] * r[2] + r[3] * r[3];
    }
    __shared__ float red[256];
    red[tid] = loss;
    __syncthreads();
    for (int s = 128; s > 0; s >>= 1) {
        if (tid < s) red[tid] += red[tid + s];
        __syncthreads();
    }
    if (tid == 0) {
        atomicAdd(lossAcc, red[0]);
        __threadfence();
        unsigned t = atomicAdd(ticket, 1u);
        if (t == NCHUNK * BDIM - 1) {
            float total = atomicAdd(lossAcc, 0.0f);   // coherent read
            out[OUT_ELEMS] = 0.5f * total / (float)OUT_ELEMS;
        }
    }
}

// ---------------------------------------------------------------------------
// Workspace layout (bytes):
//   H      (bf16 16000x1024) : 0          .. 32,768,000
//   WBT    (bf16 1024x2048)  : 32,768,000 .. 36,962,304
//   NORM   (f32 1024)        : 36,962,304 .. +4096
//   LOSS   (f32 1)           : 36,966,400
//   TICKET (u32 1)           : 36,966,404
//   CM     (f32 25*32*1024)  : 36,966,656 .. +3,276,800
//   CS                       : 40,243,456 .. +3,276,800   (end 43,520,256)
// xb (bf16 x) lives in d_out (exactly 65,536,000 B) until scan3 overwrites it.
#define OFF_H      ((size_t)0)
#define OFF_WBT    ((size_t)32768000)
#define OFF_NORM   ((size_t)36962304)
#define OFF_LOSS   ((size_t)36966400)
#define OFF_TICKET ((size_t)36966404)
#define OFF_CM     ((size_t)36966656)
#define OFF_CS     ((size_t)40243456)

extern "C" void kernel_launch(void* const* d_in, const int* in_sizes, int n_in,
                              void* d_out, int out_size, void* d_ws, size_t ws_size,
                              hipStream_t stream) {
    const float* x  = (const float*)d_in[0];
    const float* w  = (const float*)d_in[1];
    const float* bb = (const float*)d_in[2];
    const float* dm = (const float*)d_in[3];
    const float* ds = (const float*)d_in[4];

    char* ws = (char*)d_ws;
    __bf16*   H    = (__bf16*)(ws + OFF_H);
    __bf16*   WBT  = (__bf16*)(ws + OFF_WBT);
    float*    NORM = (float*)(ws + OFF_NORM);
    float*    LOSS = (float*)(ws + OFF_LOSS);
    unsigned* TICK = (unsigned*)(ws + OFF_TICKET);
    f32x4*    CM   = (f32x4*)(ws + OFF_CM);
    f32x4*    CS   = (f32x4*)(ws + OFF_CS);
    __bf16*   XB   = (__bf16*)d_out;          // scratch: bf16 x (exact fit)
    float*    out  = (float*)d_out;

    hipMemsetAsync(ws + OFF_NORM, 0, 4096 + 256, stream);   // NORM+LOSS+TICKET

    convert_x<<<16000, 256, 0, stream>>>(x, XB);
    transpose_w<<<dim3(32, 64), dim3(32, 8), 0, stream>>>(w, WBT, NORM);
    gemm_bf16<<<252, 512, 0, stream>>>(XB, WBT, H);
    scan1<<<dim3(NCHUNK, BDIM), 256, 0, stream>>>(H, CM, CS, dm, ds);
    scan2<<<128, 256, 0, stream>>>((float*)CM, (float*)CS, dm, ds);
    scan3<<<dim3(NCHUNK, BDIM), 256, 0, stream>>>(H, CM, CS, NORM, bb, dm, ds,
                                                  out, LOSS, TICK);
}

// Round 3
// 341.420 us; speedup vs baseline: 1.0587x; 1.0173x over previous
//
#include <hip/hip_runtime.h>

// ---------------------------------------------------------------------------
// STCAOutputLayer: h = x@w (bf16 MFMA GEMM); E==0 identically (spk never set),
// out[b,t,d] = (M_t - S_t)*inv_norm[d] - bias[d],
// M_t = dm*(M_{t-1}+h_t), S_t = ds*(S_{t-1}+h_t); loss = 0.5*mean(out^2).
// Shapes: B=32 T=500 IN=2048 OUT=1024; M=B*T=16000, N=1024, K=2048.
//
// R4: 256x256, 8 waves, 1 blk/CU, reads-then-MFMAs per tile -> 85.7us, 33%
//     MfmaUtil: read burst and MFMA burst serialized (first MFMA needed 9/12
//     reads), no cross-block overlap at 1 blk/CU.
// R5: 256x128 block, 256 thr (4 waves, wave 128x64), 3 bufs x 24KB = 72KB
//     -> 2 blocks/CU (cross-block overlap), rotated 2-cluster pipeline:
//     reads always issue under a non-dependent 16-MFMA cluster. Counted
//     vmcnt (never 0 mid-loop), 2 raw barriers/tile, unroll-2 named frag
//     sets. Grid 504 = 8*63 -> exact XCD swizzle.
// ---------------------------------------------------------------------------

typedef __bf16 bf16x8 __attribute__((ext_vector_type(8)));
typedef __bf16 bf16x4 __attribute__((ext_vector_type(4)));
typedef float  f32x4  __attribute__((ext_vector_type(4)));

#define BDIM 32
#define TDIM 500
#define INDIM 2048
#define OUTDIM 1024
#define MROWS 16000            // B*T
#define NCHUNK 25              // scan chunks
#define CHLEN 20               // 25*20 = 500
#define OUT_ELEMS 16384000     // B*T*OUT

// ---- global -> LDS async copy, 16B per lane, LDS dest = base + lane*16 ----
__device__ __forceinline__ void gld_lds16(const void* g, void* l) {
    __builtin_amdgcn_global_load_lds(
        (const __attribute__((address_space(1))) unsigned int*)g,
        (__attribute__((address_space(3))) unsigned int*)l, 16, 0, 0);
}

// ---------------------------------------------------------------------------
// fp32 -> bf16 convert of x (pure elementwise). 8 elems / thread.
__global__ void convert_x(const float* __restrict__ x, __bf16* __restrict__ xb) {
    size_t i = ((size_t)blockIdx.x * 256 + threadIdx.x) * 8;
    float4 a = *(const float4*)(x + i);
    float4 b = *(const float4*)(x + i + 4);
    bf16x8 o;
    o[0] = (__bf16)a.x; o[1] = (__bf16)a.y; o[2] = (__bf16)a.z; o[3] = (__bf16)a.w;
    o[4] = (__bf16)b.x; o[5] = (__bf16)b.y; o[6] = (__bf16)b.z; o[7] = (__bf16)b.w;
    *(bf16x8*)(xb + i) = o;
}

// ---------------------------------------------------------------------------
// w [K=2048][N=1024] fp32 -> wbt [N][K] bf16, with fused norm[d]=sum_c w^2
__global__ void transpose_w(const float* __restrict__ w, __bf16* __restrict__ wbt,
                            float* __restrict__ normAcc) {
    __shared__ float tile[32][33];
    __shared__ float red[8][33];
    const int tx = threadIdx.x;        // 0..31
    const int ty = threadIdx.y;        // 0..7
    const int d0 = blockIdx.x * 32;    // N tile
    const int c0 = blockIdx.y * 32;    // K tile
    float s = 0.f;
#pragma unroll
    for (int i = 0; i < 4; ++i) {
        int c = c0 + ty + i * 8;
        float v = w[(size_t)c * OUTDIM + d0 + tx];
        tile[ty + i * 8][tx] = v;
        s += v * v;
    }
    red[ty][tx] = s;
    __syncthreads();
#pragma unroll
    for (int i = 0; i < 4; ++i) {
        int d = d0 + ty + i * 8;
        wbt[(size_t)d * INDIM + c0 + tx] = (__bf16)tile[tx][ty + i * 8];
    }
    if (ty == 0) {
        float t = red[0][tx] + red[1][tx] + red[2][tx] + red[3][tx]
                + red[4][tx] + red[5][tx] + red[6][tx] + red[7][tx];
        atomicAdd(&normAcc[d0 + tx], t);
    }
}

// ---------------------------------------------------------------------------
// GEMM: H[m][n] = sum_k A[m][k]*Bt[n][k], bf16 in/out (fp32 acc).
// BM=256(m) x BN=128(n), BK=32, 4 waves, wave tile 128x64 (8x4 frags).
// 3 LDS buffers (A 16KB + B 8KB each). Rotated pipeline per tile t:
//   af1(t) reads [4]             <- issue under...
//   MFMA c0 (af0/bfr pre-read)   <- ...this cluster
//   lgkmcnt(0); barrier          <- all reads of buf[ib] drained block-wide
//   STAGE(t+3 -> buf[ib]); counted vmcnt; barrier (tile t+1 resident)
//   bfr/af0(t+1) reads [8]       <- issue under...
//   MFMA c1 (af1 x bfr(t))       <- ...this cluster
// vmcnt ladder: steady 12 (tiles t+2,t+3 in flight=12 after t+1 lands);
// never drains mid-loop. Unroll-2 ping-pongs named frag sets (rule #20).
__global__ __launch_bounds__(256, 2) void gemm_bf16(
    const __bf16* __restrict__ A,   // [16000][2048]  (xb, lives in d_out)
    const __bf16* __restrict__ Bt,  // [1024][2048]
    __bf16* __restrict__ H)         // [16000][1024]
{
    constexpr int K  = INDIM;
    constexpr int NT = K / 32;                       // 64 K-tiles
    __shared__ __align__(16) __bf16 As[3][256 * 32]; // 3 x 16KB
    __shared__ __align__(16) __bf16 Bs[3][128 * 32]; // 3 x 8KB

    const int tid  = threadIdx.x;
    const int wave = tid >> 6;          // 0..3
    const int lane = tid & 63;
    const int wm   = wave >> 1;         // 0..1 : 128-row output band
    const int wn   = wave & 1;          // 0..1 : 64-col output band

    // exact XCD swizzle: 504 blocks = 8 XCDs x 63. Within an XCD chunk,
    // consecutive wgid sweep bn fast -> A-panel reuse in that XCD's L2.
    const int orig = blockIdx.x;
    const int wgid = (orig & 7) * 63 + (orig >> 3);
    const int bm = (wgid >> 3) * 256;   // 0..15872 (last block: 128 valid rows)
    const int bn = (wgid & 7) * 128;

    // staging: one gld_lds = 1KB = 16 rows x 64B. lane -> (row=lane>>2, seg=lane&3).
    // LDS linear; swizzle via pre-swizzled GLOBAL column (m173 pattern).
    const int srow = lane >> 2;
    const int sseg = lane & 3;
    const int scol = (sseg ^ ((srow >> 1) & 3)) * 8;     // elems
    const __bf16* gA[4]; int ldsA[4];
#pragma unroll
    for (int g = 0; g < 4; ++g) {
        const int q = wave * 4 + g;                      // 0..15: A row group
        int r = bm + q * 16 + srow; if (r > MROWS - 1) r = MROWS - 1;
        gA[g]  = A + (size_t)r * K + scol;
        ldsA[g] = q * 16 * 32;
    }
    const __bf16* gB[2]; int ldsB[2];
#pragma unroll
    for (int g = 0; g < 2; ++g) {
        const int p = wave * 2 + g;                      // 0..7: B row group
        gB[g]  = Bt + (size_t)(bn + p * 16 + srow) * K + scol;
        ldsB[g] = p * 16 * 32;
    }

    // fragment reads: row = band + i*16 + mrow, seg = quad ^ ((mrow>>1)&3)
    const int mrow = lane & 15, quad = lane >> 4;
    const int swzq = quad ^ ((mrow >> 1) & 3);
    const int rdA = (wm * 128 + mrow) * 32 + swzq * 8;
    const int rdB = (wn * 64  + mrow) * 32 + swzq * 8;

    f32x4 acc[8][4] = {};
    int ib = 0;                                          // current buffer

    auto stage = [&](int tt, __bf16* as, __bf16* bs) {
        const size_t k = (size_t)tt * 32;
#pragma unroll
        for (int g = 0; g < 4; ++g) gld_lds16(gA[g] + k, as + ldsA[g]);
#pragma unroll
        for (int g = 0; g < 2; ++g) gld_lds16(gB[g] + k, bs + ldsB[g]);
    };

    // prologue: tiles 0..2 in flight; wait tile0 (12 = 2 tiles x 6 loads left)
    stage(0, &As[0][0], &Bs[0][0]);
    stage(1, &As[1][0], &Bs[1][0]);
    stage(2, &As[2][0], &Bs[2][0]);
    asm volatile("s_waitcnt vmcnt(12)" ::: "memory");
    asm volatile("s_barrier" ::: "memory");

    bf16x8 afA[4], bfA[4], afB[4], bfB[4];
    {
        const __bf16* as = &As[0][0]; const __bf16* bs = &Bs[0][0];
#pragma unroll
        for (int j = 0; j < 4; ++j) bfA[j] = *(const bf16x8*)&bs[rdB + j * 512];
#pragma unroll
        for (int i = 0; i < 4; ++i) afA[i] = *(const bf16x8*)&as[rdA + i * 512];
    }

    auto iter = [&](int T, bf16x8 (&afC)[4], bf16x8 (&bfC)[4],
                           bf16x8 (&afN)[4], bf16x8 (&bfN)[4]) {
        const __bf16* as = &As[ib][0];
        bf16x8 af1[4];
#pragma unroll
        for (int i = 0; i < 4; ++i) af1[i] = *(const bf16x8*)&as[rdA + 2048 + i * 512];
        // cluster0: pre-read frags -> LDS services af1 under these MFMAs
#pragma unroll
        for (int i = 0; i < 4; ++i)
#pragma unroll
            for (int j = 0; j < 4; ++j)
                acc[i][j] = __builtin_amdgcn_mfma_f32_16x16x32_bf16(
                    afC[i], bfC[j], acc[i][j], 0, 0, 0);
        asm volatile("s_waitcnt lgkmcnt(0)" ::: "memory");   // reads of buf[ib] drained
        asm volatile("s_barrier" ::: "memory");              // ...block-wide
        if (T + 3 < NT) stage(T + 3, &As[ib][0], &Bs[ib][0]); // overwrite freed buf
        if (T < NT - 3)      asm volatile("s_waitcnt vmcnt(12)" ::: "memory");
        else if (T == NT - 3) asm volatile("s_waitcnt vmcnt(6)" ::: "memory");
        else if (T == NT - 2) asm volatile("s_waitcnt vmcnt(0)" ::: "memory");
        ib = (ib == 2) ? 0 : ib + 1;
        if (T < NT - 1) {
            asm volatile("s_barrier" ::: "memory");          // tile T+1 resident
            const __bf16* asn = &As[ib][0]; const __bf16* bsn = &Bs[ib][0];
#pragma unroll
            for (int j = 0; j < 4; ++j) bfN[j] = *(const bf16x8*)&bsn[rdB + j * 512];
#pragma unroll
            for (int i = 0; i < 4; ++i) afN[i] = *(const bf16x8*)&asn[rdA + i * 512];
        }
        // cluster1: af1 x bfC(t) -> LDS services next-tile pre-reads under it
#pragma unroll
        for (int i = 0; i < 4; ++i)
#pragma unroll
            for (int j = 0; j < 4; ++j)
                acc[4 + i][j] = __builtin_amdgcn_mfma_f32_16x16x32_bf16(
                    af1[i], bfC[j], acc[4 + i][j], 0, 0, 0);
    };

#pragma unroll 1
    for (int t = 0; t < NT; t += 2) {
        iter(t,     afA, bfA, afB, bfB);
        iter(t + 1, afB, bfB, afA, bfA);
    }

    // epilogue: D[row=quad*4+reg][col=mrow] (m89-verified layout)
    const int Rb = bm + wm * 128 + quad * 4;
    const int Cb = bn + wn * 64 + mrow;
#pragma unroll
    for (int i = 0; i < 8; ++i)
#pragma unroll
        for (int j = 0; j < 4; ++j)
#pragma unroll
            for (int r = 0; r < 4; ++r) {
                const int R = Rb + i * 16 + r;
                if (R < MROWS)
                    H[(size_t)R * OUTDIM + Cb + j * 16] = (__bf16)acc[i][j][r];
            }
}

// ---------------------------------------------------------------------------
// scan pass 1: per (chunk c, batch b): local M/S with zero carry-in; store
// chunk-end values.  256 threads cover all 1024 d (float4 each).
__global__ void scan1(const __bf16* __restrict__ H,
                      f32x4* __restrict__ cM, f32x4* __restrict__ cS,
                      const float* __restrict__ dmp, const float* __restrict__ dsp) {
    const float dm = *dmp, ds = *dsp;
    const int c = blockIdx.x, b = blockIdx.y, tid = threadIdx.x;
    f32x4 M = {}, S = {};
    const __bf16* p = H + ((size_t)b * TDIM + c * CHLEN) * OUTDIM + tid * 4;
#pragma unroll 4
    for (int t = 0; t < CHLEN; ++t) {
        bf16x4 hv = *(const bf16x4*)(p + (size_t)t * OUTDIM);
        f32x4 h; h[0] = hv[0]; h[1] = hv[1]; h[2] = hv[2]; h[3] = hv[3];
        M = dm * (M + h);
        S = ds * (S + h);
    }
    const size_t idx = ((size_t)c * BDIM + b) * 256 + tid;
    cM[idx] = M;
    cS[idx] = S;
}

// ---------------------------------------------------------------------------
// scan pass 2: chunk-end values -> per-chunk carry-INs (in place).
__global__ void scan2(float* __restrict__ cM, float* __restrict__ cS,
                      const float* __restrict__ dmp, const float* __restrict__ dsp) {
    const float dm = *dmp, ds = *dsp;
    float km = 1.f, ks = 1.f;
#pragma unroll
    for (int i = 0; i < CHLEN; ++i) { km *= dm; ks *= ds; }
    const int gid = blockIdx.x * 256 + threadIdx.x;   // 0..32767
    const int b = gid >> 10, d = gid & 1023;
    float tM = 0.f, tS = 0.f;
    for (int c = 0; c < NCHUNK; ++c) {
        const size_t idx = (((size_t)c * BDIM + b) << 10) + d;
        float oM = cM[idx], oS = cS[idx];
        cM[idx] = tM; cS[idx] = tS;
        tM = km * tM + oM;
        tS = ks * tS + oS;
    }
}

// ---------------------------------------------------------------------------
// scan pass 3: recompute with carry-in, write out, accumulate loss; last
// block (device-scope ticket) writes the final loss scalar.
__global__ void scan3(const __bf16* __restrict__ H,
                      const f32x4* __restrict__ cM, const f32x4* __restrict__ cS,
                      const float* __restrict__ normAcc, const float* __restrict__ bias,
                      const float* __restrict__ dmp, const float* __restrict__ dsp,
                      float* __restrict__ out, float* __restrict__ lossAcc,
                      unsigned* __restrict__ ticket) {
    const float dm = *dmp, ds = *dsp;
    const int c = blockIdx.x, b = blockIdx.y, tid = threadIdx.x;
    const size_t cidx = ((size_t)c * BDIM + b) * 256 + tid;
    f32x4 M = cM[cidx];
    f32x4 S = cS[cidx];
    f32x4 nv = *(const f32x4*)(normAcc + tid * 4);
    f32x4 inv;
    inv[0] = 1.f / (nv[0] + 1e-8f); inv[1] = 1.f / (nv[1] + 1e-8f);
    inv[2] = 1.f / (nv[2] + 1e-8f); inv[3] = 1.f / (nv[3] + 1e-8f);
    f32x4 bv = *(const f32x4*)(bias + tid * 4);

    const size_t rowbase = ((size_t)b * TDIM + c * CHLEN) * OUTDIM + tid * 4;
    const __bf16* p = H + rowbase;
    float* o = out + rowbase;
    float loss = 0.f;
#pragma unroll 4
    for (int t = 0; t < CHLEN; ++t) {
        bf16x4 hv = *(const bf16x4*)(p + (size_t)t * OUTDIM);
        f32x4 h; h[0] = hv[0]; h[1] = hv[1]; h[2] = hv[2]; h[3] = hv[3];
        M = dm * (M + h);
        S = ds * (S + h);
        f32x4 r = (M - S) * inv - bv;
        *(f32x4*)(o + (size_t)t * OUTDIM) = r;
        loss += r[0] * r[0] + r[1] * r[1] + r[2] * r[2] + r[3] * r[3];
    }
    __shared__ float red[256];
    red[tid] = loss;
    __syncthreads();
    for (int s = 128; s > 0; s >>= 1) {
        if (tid < s) red[tid] += red[tid + s];
        __syncthreads();
    }
    if (tid == 0) {
        atomicAdd(lossAcc, red[0]);
        __threadfence();
        unsigned t = atomicAdd(ticket, 1u);
        if (t == NCHUNK * BDIM - 1) {
            float total = atomicAdd(lossAcc, 0.0f);   // coherent read
            out[OUT_ELEMS] = 0.5f * total / (float)OUT_ELEMS;
        }
    }
}

// ---------------------------------------------------------------------------
// Workspace layout (bytes):
//   H      (bf16 16000x1024) : 0          .. 32,768,000
//   WBT    (bf16 1024x2048)  : 32,768,000 .. 36,962,304
//   NORM   (f32 1024)        : 36,962,304 .. +4096
//   LOSS   (f32 1)           : 36,966,400
//   TICKET (u32 1)           : 36,966,404
//   CM     (f32 25*32*1024)  : 36,966,656 .. +3,276,800
//   CS                       : 40,243,456 .. +3,276,800   (end 43,520,256)
// xb (bf16 x) lives in d_out (exactly 65,536,000 B) until scan3 overwrites it.
#define OFF_H      ((size_t)0)
#define OFF_WBT    ((size_t)32768000)
#define OFF_NORM   ((size_t)36962304)
#define OFF_LOSS   ((size_t)36966400)
#define OFF_TICKET ((size_t)36966404)
#define OFF_CM     ((size_t)36966656)
#define OFF_CS     ((size_t)40243456)

extern "C" void kernel_launch(void* const* d_in, const int* in_sizes, int n_in,
                              void* d_out, int out_size, void* d_ws, size_t ws_size,
                              hipStream_t stream) {
    const float* x  = (const float*)d_in[0];
    const float* w  = (const float*)d_in[1];
    const float* bb = (const float*)d_in[2];
    const float* dm = (const float*)d_in[3];
    const float* ds = (const float*)d_in[4];

    char* ws = (char*)d_ws;
    __bf16*   H    = (__bf16*)(ws + OFF_H);
    __bf16*   WBT  = (__bf16*)(ws + OFF_WBT);
    float*    NORM = (float*)(ws + OFF_NORM);
    float*    LOSS = (float*)(ws + OFF_LOSS);
    unsigned* TICK = (unsigned*)(ws + OFF_TICKET);
    f32x4*    CM   = (f32x4*)(ws + OFF_CM);
    f32x4*    CS   = (f32x4*)(ws + OFF_CS);
    __bf16*   XB   = (__bf16*)d_out;          // scratch: bf16 x (exact fit)
    float*    out  = (float*)d_out;

    hipMemsetAsync(ws + OFF_NORM, 0, 4096 + 256, stream);   // NORM+LOSS+TICKET

    convert_x<<<16000, 256, 0, stream>>>(x, XB);
    transpose_w<<<dim3(32, 64), dim3(32, 8), 0, stream>>>(w, WBT, NORM);
    gemm_bf16<<<504, 256, 0, stream>>>(XB, WBT, H);
    scan1<<<dim3(NCHUNK, BDIM), 256, 0, stream>>>(H, CM, CS, dm, ds);
    scan2<<<128, 256, 0, stream>>>((float*)CM, (float*)CS, dm, ds);
    scan3<<<dim3(NCHUNK, BDIM), 256, 0, stream>>>(H, CM, CS, NORM, bb, dm, ds,
                                                  out, LOSS, TICK);
}